// Round 1
// baseline (43.895 us; speedup 1.0000x reference)
//
#include <hip/hip_runtime.h>
#include <stdint.h>

#define KSEL 10
#define NTHREADS 256
#define CAP 2560            // candidate slots; also exactly fits fallback dump 256*10
#define BUFSZ (CAP + 16)

__device__ __forceinline__ unsigned long long ullmin(unsigned long long a, unsigned long long b) {
    return a < b ? a : b;
}

__global__ void __launch_bounds__(NTHREADS)
knn_topk_kernel(const float* __restrict__ ged, const float* __restrict__ y,
                const float* __restrict__ coef, float* __restrict__ out, int n_train)
{
    __shared__ unsigned long long sbuf[BUFSZ];
    __shared__ unsigned long long wmin[NTHREADS / 64];
    __shared__ unsigned long long winner;
    __shared__ unsigned long long topk[KSEL];
    __shared__ int cnt;

    const int tid = threadIdx.x;
    const int row = blockIdx.x;
    const float* __restrict__ x = ged + (size_t)row * (size_t)n_train;

    // vector path only if the tail/alignment works out (true here: 50000 % 4 == 0)
    const int n4 = ((n_train & 3) == 0) ? (n_train >> 2) : 0;
    const float4* __restrict__ x4 = (const float4*)x;

    int len = -1;
    float T = 2.0e-3f;

    for (int attempt = 0; attempt < 24; ++attempt) {
        if (tid == 0) cnt = 0;
        __syncthreads();

        for (int i = tid; i < n4; i += NTHREADS) {
            float4 v = x4[i];
            int base = i << 2;
            if (v.x < T) { int p = atomicAdd(&cnt, 1); if (p < CAP) sbuf[p] = ((unsigned long long)__float_as_uint(v.x) << 32) | (unsigned)(base    ); }
            if (v.y < T) { int p = atomicAdd(&cnt, 1); if (p < CAP) sbuf[p] = ((unsigned long long)__float_as_uint(v.y) << 32) | (unsigned)(base + 1); }
            if (v.z < T) { int p = atomicAdd(&cnt, 1); if (p < CAP) sbuf[p] = ((unsigned long long)__float_as_uint(v.z) << 32) | (unsigned)(base + 2); }
            if (v.w < T) { int p = atomicAdd(&cnt, 1); if (p < CAP) sbuf[p] = ((unsigned long long)__float_as_uint(v.w) << 32) | (unsigned)(base + 3); }
        }
        for (int i = (n4 << 2) + tid; i < n_train; i += NTHREADS) {
            float v = x[i];
            if (v < T) { int p = atomicAdd(&cnt, 1); if (p < CAP) sbuf[p] = ((unsigned long long)__float_as_uint(v) << 32) | (unsigned)i; }
        }
        __syncthreads();

        int c = cnt;                         // uniform across block
        if (c >= KSEL && c <= CAP) { len = c; break; }
        T = (c < KSEL) ? T * 8.0f : T * 0.125f;
        __syncthreads();                     // protect cnt until everyone read it
    }

    if (len < 0) {
        // Exact fallback (any data distribution): per-thread sorted top-K, then merge.
        unsigned long long loc[KSEL];
        #pragma unroll
        for (int j = 0; j < KSEL; ++j) loc[j] = ~0ull;
        for (int i = tid; i < n_train; i += NTHREADS) {
            unsigned long long key = ((unsigned long long)__float_as_uint(x[i]) << 32) | (unsigned)i;
            if (key < loc[KSEL - 1]) {
                loc[KSEL - 1] = key;
                #pragma unroll
                for (int j = KSEL - 1; j > 0; --j) {
                    if (loc[j] < loc[j - 1]) {
                        unsigned long long t = loc[j]; loc[j] = loc[j - 1]; loc[j - 1] = t;
                    }
                }
            }
        }
        __syncthreads();
        #pragma unroll
        for (int j = 0; j < KSEL; ++j) sbuf[tid * KSEL + j] = loc[j];
        __syncthreads();
        len = NTHREADS * KSEL;
    }

    // Extract KSEL smallest keys from sbuf[0..len) — 10 rounds of min-with-removal.
    for (int r = 0; r < KSEL; ++r) {
        unsigned long long m = ~0ull;
        for (int j = tid; j < len; j += NTHREADS) m = ullmin(m, sbuf[j]);
        #pragma unroll
        for (int off = 32; off > 0; off >>= 1) m = ullmin(m, __shfl_down(m, off, 64));
        if ((tid & 63) == 0) wmin[tid >> 6] = m;
        __syncthreads();
        if (tid == 0) {
            unsigned long long w = wmin[0];
            #pragma unroll
            for (int q = 1; q < NTHREADS / 64; ++q) w = ullmin(w, wmin[q]);
            winner = w;
            topk[r] = w;
        }
        __syncthreads();
        unsigned long long w = winner;
        for (int j = tid; j < len; j += NTHREADS) if (sbuf[j] == w) sbuf[j] = ~0ull;
        __syncthreads();
    }

    if (tid == 0) {
        float cd = coef[0];
        float alpha = cd * cd;
        float ssum = 0.0f, swy = 0.0f;
        #pragma unroll
        for (int r = 0; r < KSEL; ++r) {
            unsigned long long key = topk[r];
            float v = __uint_as_float((unsigned)(key >> 32));
            int idx = (int)(unsigned)(key & 0xffffffffull);
            float s = expf(-alpha * v);
            ssum += s;
            swy  += s * y[idx];
        }
        out[row] = swy / ssum;
    }
}

extern "C" void kernel_launch(void* const* d_in, const int* in_sizes, int n_in,
                              void* d_out, int out_size, void* d_ws, size_t ws_size,
                              hipStream_t stream) {
    const float* ged  = (const float*)d_in[0];
    const float* y    = (const float*)d_in[1];
    const float* coef = (const float*)d_in[2];
    float* out = (float*)d_out;

    const int rows    = out_size;              // = NB_TEST = 1024
    const int n_train = in_sizes[0] / rows;    // = 50000

    knn_topk_kernel<<<rows, NTHREADS, 0, stream>>>(ged, y, coef, out, n_train);
}